// Round 9
// baseline (448.388 us; speedup 1.0000x reference)
//
#include <hip/hip_runtime.h>
#include <math.h>

#define N_NODES 100000
#define NBUCK ((N_NODES + 255) / 256)   // 391 dst-buckets of 256 nodes
#define CAP 8192                        // slots per bucket (mean 4096, +64 sigma)
#define ACHUNK 1024                     // edges per pass-A block (small: keeps CUs oversubscribed)

struct alignas(16) f4 { float v[4]; };
struct alignas(8) us4 { unsigned short v[4]; };

__device__ inline unsigned short f2bf(float x) {
    union { float f; unsigned int u; } v;
    v.f = x;
    unsigned int r = v.u + 0x7FFF + ((v.u >> 16) & 1);
    return (unsigned short)(r >> 16);
}

__device__ inline float bf2f(unsigned short h) {
    union { unsigned int u; float f; } v;
    v.u = ((unsigned int)h) << 16;
    return v.f;
}

// ---------------- K1: interleaved [bucketed edge partition + degs atomics] + layer-0 GEMM ----------------
__global__ __launch_bounds__(256, 4) void k_passA_gemm0(const int* __restrict__ src,
                                                        const int* __restrict__ dst,
                                                        int E, int nchunk, int S,
                                                        int* __restrict__ degs,
                                                        int* __restrict__ bcur,
                                                        int* __restrict__ packed,
                                                        const float* __restrict__ A,
                                                        const float* __restrict__ W,
                                                        unsigned short* __restrict__ C,
                                                        int n) {
    __shared__ __align__(16) float Ws[64 * 64];
    __shared__ __align__(16) float Asm[64 * 68];

    const int tid = threadIdx.x;
    const int b = blockIdx.x;

    if ((b % S == 0) && (b / S < nchunk)) {
        // ---- pass A: bucketed partition ----
        int* hist = (int*)Ws;          // NBUCK
        int* cur = hist + NBUCK;       // NBUCK
        const int base = (b / S) * ACHUNK;
        const int lim = min(E, base + ACHUNK);

        for (int i = tid; i < NBUCK; i += 256) hist[i] = 0;
        __syncthreads();
        for (int i = base + tid; i < lim; i += 256) {
            int s = src[i];
            int d = dst[i];
            atomicAdd(&degs[s], 1);          // global, fire-and-forget
            atomicAdd(&hist[d >> 8], 1);     // LDS
        }
        __syncthreads();
        for (int i = tid; i < NBUCK; i += 256) {
            int c = hist[i];
            cur[i] = (c > 0) ? atomicAdd(&bcur[i], c) : 0;  // bulk reservation
        }
        __syncthreads();
        for (int i = base + tid; i < lim; i += 256) {
            int s = src[i];
            int d = dst[i];
            int bk = d >> 8;
            int p = atomicAdd(&cur[bk], 1);  // LDS
            packed[(size_t)bk * CAP + p] = (s << 8) | (d & 255);
        }
        return;
    }

    // ---- GEMM tile ----
    const int nA = min((b + S - 1) / S, nchunk);  // pass-A ids below b
    const int r0 = (b - nA) * 64;
    const int tr = tid >> 4;
    const int tc = tid & 15;

    float acc[4][4];
#pragma unroll
    for (int i = 0; i < 4; ++i)
#pragma unroll
        for (int j = 0; j < 4; ++j) acc[i][j] = 0.0f;

    for (int kh = 0; kh < 2; ++kh) {
        for (int i = tid; i < 64 * 64; i += 256) {
            int k = i >> 6;
            int c = i & 63;
            Ws[i] = W[(kh * 64 + k) * 64 + c];
        }
        for (int i = tid * 4; i < 64 * 64; i += 1024) {
            int r = i >> 6;
            int c = i & 63;
            f4 v;
            if (r0 + r < n) {
                v = *(const f4*)&A[(size_t)(r0 + r) * 128 + kh * 64 + c];
            } else {
                v.v[0] = v.v[1] = v.v[2] = v.v[3] = 0.0f;
            }
            *(f4*)&Asm[r * 68 + c] = v;
        }
        __syncthreads();

        for (int k = 0; k < 64; k += 4) {
            f4 av[4], wv[4];
#pragma unroll
            for (int i = 0; i < 4; ++i)
                av[i] = *(const f4*)&Asm[(tr * 4 + i) * 68 + k];
#pragma unroll
            for (int kk = 0; kk < 4; ++kk)
                wv[kk] = *(const f4*)&Ws[(k + kk) * 64 + tc * 4];
#pragma unroll
            for (int i = 0; i < 4; ++i)
#pragma unroll
                for (int j = 0; j < 4; ++j)
                    acc[i][j] += av[i].v[0] * wv[0].v[j] + av[i].v[1] * wv[1].v[j] +
                                 av[i].v[2] * wv[2].v[j] + av[i].v[3] * wv[3].v[j];
        }
        __syncthreads();
    }

#pragma unroll
    for (int i = 0; i < 4; ++i) {
        int row = r0 + tr * 4 + i;
        if (row < n) {
            us4 o;
#pragma unroll
            for (int j = 0; j < 4; ++j) o.v[j] = f2bf(acc[i][j]);
            *(us4*)&C[(size_t)row * 64 + tc * 4] = o;
        }
    }
}

// ---------------- K2: per-bucket CSR build + norms + H ns-scale ----------------
__global__ __launch_bounds__(256) void k_passB(const int* __restrict__ bcur,
                                               const int* __restrict__ packed,
                                               const int* __restrict__ degs,
                                               int* __restrict__ csr_src,
                                               int* __restrict__ row_beg,
                                               int* __restrict__ row_end,
                                               float* __restrict__ ns,
                                               float* __restrict__ nd,
                                               unsigned int* __restrict__ Hd,
                                               int n) {
    __shared__ int cnt[256];
    __shared__ int sc[256];
    __shared__ int cur[256];
    __shared__ float nsf[256];

    const int b = blockIdx.x;
    const int tid = threadIdx.x;
    const int n0 = b * 256;
    const int nn = min(256, n - n0);
    const int m = min(bcur[b], CAP);
    const int* pk = packed + (size_t)b * CAP;

    cnt[tid] = 0;
    __syncthreads();
    for (int i = tid; i < m; i += 256) atomicAdd(&cnt[pk[i] & 255], 1);
    __syncthreads();
    int c = cnt[tid];
    sc[tid] = c;
    __syncthreads();
    for (int off = 1; off < 256; off <<= 1) {
        int t = (tid >= off) ? sc[tid - off] : 0;
        __syncthreads();
        sc[tid] += t;
        __syncthreads();
    }
    int excl = sc[tid] - c;
    cur[tid] = excl;
    if (tid < nn) {
        int v = n0 + tid;
        int beg = b * CAP + excl;
        row_beg[v] = beg;
        row_end[v] = beg + c;
        nd[v] = (c > 0) ? rsqrtf((float)c) : 0.0f;
        int dg = degs[v];
        float s = (dg > 0) ? rsqrtf((float)dg) : 0.0f;
        ns[v] = s;
        nsf[tid] = s;
    } else {
        nsf[tid] = 0.0f;
    }
    __syncthreads();
    for (int i = tid; i < m; i += 256) {
        int w = pk[i];
        int v = w & 255;
        int p = atomicAdd(&cur[v], 1);  // LDS
        csr_src[(size_t)b * CAP + p] = w >> 8;
    }
    // scale H rows of this bucket's nodes by ns (deferred layer-0 scale)
    for (int i = tid; i < nn * 32; i += 256) {
        int r = i >> 5;
        float s = nsf[r];
        size_t gi = (size_t)(n0 + r) * 32 + (i & 31);
        unsigned int u = Hd[gi];
        float lo = bf2f((unsigned short)(u & 0xffffu)) * s;
        float hi = bf2f((unsigned short)(u >> 16)) * s;
        Hd[gi] = (unsigned int)f2bf(lo) | ((unsigned int)f2bf(hi) << 16);
    }
}

// ---------------- GEMM (K=64): C = bf16((A @ W) * ns[row]) ----------------
template <int OUT>
__global__ __launch_bounds__(256, 4) void k_gemm_scale(const float* __restrict__ A,
                                                       const float* __restrict__ W,
                                                       const float* __restrict__ ns,
                                                       unsigned short* __restrict__ C,
                                                       int n) {
    __shared__ __align__(16) float Ws[64 * 64];
    __shared__ __align__(16) float Asm[64 * 68];

    const int tid = threadIdx.x;
    const int r0 = blockIdx.x * 64;

    for (int i = tid; i < 64 * 64; i += 256) {
        int k = i >> 6;
        int c = i & 63;
        Ws[i] = (c < OUT) ? W[k * OUT + c] : 0.0f;
    }
    for (int i = tid * 4; i < 64 * 64; i += 1024) {
        int r = i >> 6;
        int c = i & 63;
        f4 v;
        if (r0 + r < n) {
            v = *(const f4*)&A[(size_t)(r0 + r) * 64 + c];
        } else {
            v.v[0] = v.v[1] = v.v[2] = v.v[3] = 0.0f;
        }
        *(f4*)&Asm[r * 68 + c] = v;
    }
    __syncthreads();

    const int tr = tid >> 4;
    const int tc = tid & 15;

    float acc[4][4];
#pragma unroll
    for (int i = 0; i < 4; ++i)
#pragma unroll
        for (int j = 0; j < 4; ++j) acc[i][j] = 0.0f;

    for (int k = 0; k < 64; k += 4) {
        f4 av[4], wv[4];
#pragma unroll
        for (int i = 0; i < 4; ++i)
            av[i] = *(const f4*)&Asm[(tr * 4 + i) * 68 + k];
#pragma unroll
        for (int kk = 0; kk < 4; ++kk)
            wv[kk] = *(const f4*)&Ws[(k + kk) * 64 + tc * 4];
#pragma unroll
        for (int i = 0; i < 4; ++i)
#pragma unroll
            for (int j = 0; j < 4; ++j)
                acc[i][j] += av[i].v[0] * wv[0].v[j] + av[i].v[1] * wv[1].v[j] +
                             av[i].v[2] * wv[2].v[j] + av[i].v[3] * wv[3].v[j];
    }

    if (tc * 4 < OUT) {
#pragma unroll
        for (int i = 0; i < 4; ++i) {
            int row = r0 + tr * 4 + i;
            if (row < n) {
                float s = ns[row];
                us4 o;
#pragma unroll
                for (int j = 0; j < 4; ++j) o.v[j] = f2bf(acc[i][j] * s);
                *(us4*)&C[(size_t)row * OUT + tc * 4] = o;
            }
        }
    }
}

// ---------------- fused CSR aggregate (bf16 gather) + (*nd + b) + relu? + log_softmax ----------------
// One node per 64-lane wave; per-lane vector index load + __shfl broadcast (ds_bpermute —
// lane-addressed, coherent; NO wave-uniform s_load of launch-rewritten buffers, see R8 lesson).
// 8 independent accumulators -> 8 H-gathers in flight.
template <int D, bool RELU>
__global__ __launch_bounds__(256) void k_agg_post(const int* __restrict__ row_beg,
                                                  const int* __restrict__ row_end,
                                                  const int* __restrict__ csr_src,
                                                  const unsigned short* __restrict__ H,
                                                  const float* __restrict__ nd,
                                                  const float* __restrict__ b,
                                                  float* __restrict__ Out,
                                                  int n) {
    int node = blockIdx.x * 4 + (threadIdx.x >> 6);
    int lane = threadIdx.x & 63;
    if (node >= n) return;

    int beg = row_beg[node];
    int end = row_end[node];
    bool active = lane < D;

    float a0 = 0.f, a1 = 0.f, a2 = 0.f, a3 = 0.f;
    float a4 = 0.f, a5 = 0.f, a6 = 0.f, a7 = 0.f;
    for (int i = beg; i < end; i += 64) {
        int cnt = min(64, end - i);
        int idx = (lane < cnt) ? csr_src[i + lane] : 0;
        int j = 0;
        for (; j + 8 <= cnt; j += 8) {
            int s0 = __shfl(idx, j);
            int s1 = __shfl(idx, j + 1);
            int s2 = __shfl(idx, j + 2);
            int s3 = __shfl(idx, j + 3);
            int s4 = __shfl(idx, j + 4);
            int s5 = __shfl(idx, j + 5);
            int s6 = __shfl(idx, j + 6);
            int s7 = __shfl(idx, j + 7);
            if (active) {
                a0 += bf2f(H[(size_t)s0 * D + lane]);
                a1 += bf2f(H[(size_t)s1 * D + lane]);
                a2 += bf2f(H[(size_t)s2 * D + lane]);
                a3 += bf2f(H[(size_t)s3 * D + lane]);
                a4 += bf2f(H[(size_t)s4 * D + lane]);
                a5 += bf2f(H[(size_t)s5 * D + lane]);
                a6 += bf2f(H[(size_t)s6 * D + lane]);
                a7 += bf2f(H[(size_t)s7 * D + lane]);
            }
        }
        for (; j < cnt; ++j) {
            int s = __shfl(idx, j);
            if (active) a0 += bf2f(H[(size_t)s * D + lane]);
        }
    }
    float acc = ((a0 + a1) + (a2 + a3)) + ((a4 + a5) + (a6 + a7));

    float x = -INFINITY;
    if (active) {
        x = acc * nd[node] + b[lane];
        if (RELU) x = fmaxf(x, 0.0f);
    }
    float m = x;
#pragma unroll
    for (int off = 32; off > 0; off >>= 1) m = fmaxf(m, __shfl_xor(m, off));
    float ex = active ? expf(x - m) : 0.0f;
    float ssum = ex;
#pragma unroll
    for (int off = 32; off > 0; off >>= 1) ssum += __shfl_xor(ssum, off);
    if (active) Out[(size_t)node * D + lane] = (x - m) - logf(ssum);
}

extern "C" void kernel_launch(void* const* d_in, const int* in_sizes, int n_in,
                              void* d_out, int out_size, void* d_ws, size_t ws_size,
                              hipStream_t stream) {
    const float* feats = (const float*)d_in[0];
    const int* src = (const int*)d_in[1];
    const int* dst = (const int*)d_in[2];
    const float* W0 = (const float*)d_in[3];
    const float* b0 = (const float*)d_in[4];
    const float* W1 = (const float*)d_in[5];
    const float* b1 = (const float*)d_in[6];
    const float* W2 = (const float*)d_in[7];
    const float* b2 = (const float*)d_in[8];
    float* out = (float*)d_out;

    const int N = N_NODES;
    const int E = in_sizes[1];
    const int GT = (N + 63) / 64;                       // 1563 gemm tiles
    const int NCHUNK = (E + ACHUNK - 1) / ACHUNK;       // 1563 pass-A chunks
    const int grid1 = GT + NCHUNK;
    int S = grid1 / NCHUNK;                             // interleave stride (=2)
    if (S < 1) S = 1;

    // workspace layout (~66 MB)
    float* ns = (float*)d_ws;                           // N
    float* nd = ns + N;                                 // N
    unsigned short* Hb = (unsigned short*)(nd + N);     // N*64 bf16
    float* G = (float*)(Hb + (size_t)N * 64);           // N*64 fp32
    int* packed = (int*)(G + (size_t)N * 64);           // NBUCK*CAP
    int* csr_src = packed + (size_t)NBUCK * CAP;        // NBUCK*CAP
    int* row_beg = csr_src + (size_t)NBUCK * CAP;       // N
    int* row_end = row_beg + N;                         // N
    int* degs = row_end + N;                            // N
    int* bcur = degs + N;                               // NBUCK

    hipMemsetAsync(degs, 0, (size_t)N * sizeof(int), stream);
    hipMemsetAsync(bcur, 0, (size_t)NBUCK * sizeof(int), stream);

    // 1) interleaved bucketed-partition + degs atomics + layer-0 GEMM (unscaled)
    k_passA_gemm0<<<grid1, 256, 0, stream>>>(src, dst, E, NCHUNK, S, degs, bcur,
                                             packed, feats, W0, Hb, N);

    // 2) per-bucket CSR build + norms + H ns-scale
    k_passB<<<NBUCK, 256, 0, stream>>>(bcur, packed, degs, csr_src, row_beg, row_end,
                                       ns, nd, (unsigned int*)Hb, N);

    const int agg_blocks = (N + 3) / 4;

    // ---- layer 0 agg + relu + log_softmax -> G ----
    k_agg_post<64, true><<<agg_blocks, 256, 0, stream>>>(row_beg, row_end, csr_src, Hb, nd, b0, G, N);

    // ---- layer 1 ----
    k_gemm_scale<64><<<GT, 256, 0, stream>>>(G, W1, ns, Hb, N);
    k_agg_post<64, true><<<agg_blocks, 256, 0, stream>>>(row_beg, row_end, csr_src, Hb, nd, b1, G, N);

    // ---- layer 2 ----
    k_gemm_scale<40><<<GT, 256, 0, stream>>>(G, W2, ns, Hb, N);
    k_agg_post<40, false><<<agg_blocks, 256, 0, stream>>>(row_beg, row_end, csr_src, Hb, nd, b2, out, N);
}

// Round 10
// 417.176 us; speedup vs baseline: 1.0748x; 1.0748x over previous
//
#include <hip/hip_runtime.h>
#include <math.h>

#define N_NODES 100000
#define NBUCK ((N_NODES + 255) / 256)   // 391 buckets of 256 nodes (both src and dst partitions)
#define CAP 8192                        // slots per bucket (mean 4096, +64 sigma)
#define ACHUNK 1024                     // edges per pass-A block (small: keeps CUs oversubscribed)

struct alignas(16) f4 { float v[4]; };
struct alignas(8) us4 { unsigned short v[4]; };

__device__ inline unsigned short f2bf(float x) {
    union { float f; unsigned int u; } v;
    v.f = x;
    unsigned int r = v.u + 0x7FFF + ((v.u >> 16) & 1);
    return (unsigned short)(r >> 16);
}

__device__ inline float bf2f(unsigned short h) {
    union { unsigned int u; float f; } v;
    v.u = ((unsigned int)h) << 16;
    return v.f;
}

// ---------------- K1: interleaved [dual bucketed edge partition] + layer-0 GEMM ----------------
// Chunk blocks (b%S==0): ACHUNK edges -> LDS histograms over dst-buckets AND src-buckets,
// bulk-reserve ranges in bcur/bcurS (hot-line atomics, deterministic totals), then write
// packed (src<<8|dst&255) into dst-bucket regions and (src&255) bytes into src-bucket
// regions. NO per-edge global atomics (degs eliminated — out-degree counted in pass B).
// Other blocks: 64x64 GEMM tile of Hb0 = bf16(feats @ W0), unscaled (ns applied later).
__global__ __launch_bounds__(256, 4) void k_passA_gemm0(const int* __restrict__ src,
                                                        const int* __restrict__ dst,
                                                        int E, int nchunk, int S,
                                                        int* __restrict__ bcur,
                                                        int* __restrict__ bcurS,
                                                        int* __restrict__ packed,
                                                        unsigned char* __restrict__ packedS,
                                                        const float* __restrict__ A,
                                                        const float* __restrict__ W,
                                                        unsigned short* __restrict__ C,
                                                        int n) {
    __shared__ __align__(16) float Ws[64 * 64];
    __shared__ __align__(16) float Asm[64 * 68];

    const int tid = threadIdx.x;
    const int b = blockIdx.x;

    if ((b % S == 0) && (b / S < nchunk)) {
        // ---- pass A: dual bucketed partition (uses first ~6.3 KB of Ws as int scratch) ----
        int* hist = (int*)Ws;            // NBUCK
        int* cur = hist + NBUCK;         // NBUCK
        int* histS = cur + NBUCK;        // NBUCK
        int* curS = histS + NBUCK;       // NBUCK
        const int base = (b / S) * ACHUNK;
        const int lim = min(E, base + ACHUNK);

        for (int i = tid; i < NBUCK; i += 256) { hist[i] = 0; histS[i] = 0; }
        __syncthreads();
        for (int i = base + tid; i < lim; i += 256) {
            int s = src[i];
            int d = dst[i];
            atomicAdd(&hist[d >> 8], 1);     // LDS
            atomicAdd(&histS[s >> 8], 1);    // LDS
        }
        __syncthreads();
        for (int i = tid; i < NBUCK; i += 256) {
            int c = hist[i];
            cur[i] = (c > 0) ? atomicAdd(&bcur[i], c) : 0;     // hot-line global
            int cS = histS[i];
            curS[i] = (cS > 0) ? atomicAdd(&bcurS[i], cS) : 0; // hot-line global
        }
        __syncthreads();
        for (int i = base + tid; i < lim; i += 256) {
            int s = src[i];
            int d = dst[i];
            int bk = d >> 8;
            int p = atomicAdd(&cur[bk], 1);  // LDS
            packed[(size_t)bk * CAP + p] = (s << 8) | (d & 255);
            int bs = s >> 8;
            int q = atomicAdd(&curS[bs], 1); // LDS
            packedS[(size_t)bs * CAP + q] = (unsigned char)(s & 255);
        }
        return;
    }

    // ---- GEMM tile ----
    const int nA = min((b + S - 1) / S, nchunk);  // pass-A ids below b
    const int r0 = (b - nA) * 64;
    const int tr = tid >> 4;
    const int tc = tid & 15;

    float acc[4][4];
#pragma unroll
    for (int i = 0; i < 4; ++i)
#pragma unroll
        for (int j = 0; j < 4; ++j) acc[i][j] = 0.0f;

    for (int kh = 0; kh < 2; ++kh) {
        for (int i = tid; i < 64 * 64; i += 256) {
            int k = i >> 6;
            int c = i & 63;
            Ws[i] = W[(kh * 64 + k) * 64 + c];
        }
        for (int i = tid * 4; i < 64 * 64; i += 1024) {
            int r = i >> 6;
            int c = i & 63;
            f4 v;
            if (r0 + r < n) {
                v = *(const f4*)&A[(size_t)(r0 + r) * 128 + kh * 64 + c];
            } else {
                v.v[0] = v.v[1] = v.v[2] = v.v[3] = 0.0f;
            }
            *(f4*)&Asm[r * 68 + c] = v;
        }
        __syncthreads();

        for (int k = 0; k < 64; k += 4) {
            f4 av[4], wv[4];
#pragma unroll
            for (int i = 0; i < 4; ++i)
                av[i] = *(const f4*)&Asm[(tr * 4 + i) * 68 + k];
#pragma unroll
            for (int kk = 0; kk < 4; ++kk)
                wv[kk] = *(const f4*)&Ws[(k + kk) * 64 + tc * 4];
#pragma unroll
            for (int i = 0; i < 4; ++i)
#pragma unroll
                for (int j = 0; j < 4; ++j)
                    acc[i][j] += av[i].v[0] * wv[0].v[j] + av[i].v[1] * wv[1].v[j] +
                                 av[i].v[2] * wv[2].v[j] + av[i].v[3] * wv[3].v[j];
        }
        __syncthreads();
    }

#pragma unroll
    for (int i = 0; i < 4; ++i) {
        int row = r0 + tr * 4 + i;
        if (row < n) {
            us4 o;
#pragma unroll
            for (int j = 0; j < 4; ++j) o.v[j] = f2bf(acc[i][j]);
            *(us4*)&C[(size_t)row * 64 + tc * 4] = o;
        }
    }
}

// ---------------- K2: per-bucket CSR build + norms (no H-scale here) ----------------
// Block b owns nodes [b*256, b*256+256): counts dst-partition -> row_beg/row_end/nd,
// counts src-partition bytes -> out-degree -> ns, scatters csr_src via LDS cursors.
// bcur/bcurS content is deterministic (sums); packed/packedS are read per-lane (vector
// path) because their ORDER is nondeterministic (R8 lesson: no s_load of such buffers).
__global__ __launch_bounds__(256) void k_passB(const int* __restrict__ bcur,
                                               const int* __restrict__ bcurS,
                                               const int* __restrict__ packed,
                                               const unsigned char* __restrict__ packedS,
                                               int* __restrict__ csr_src,
                                               int* __restrict__ row_beg,
                                               int* __restrict__ row_end,
                                               float* __restrict__ ns,
                                               float* __restrict__ nd,
                                               int n) {
    __shared__ int cnt[256];
    __shared__ int sc[256];
    __shared__ int cur[256];
    __shared__ int cntS[256];

    const int b = blockIdx.x;
    const int tid = threadIdx.x;
    const int n0 = b * 256;
    const int nn = min(256, n - n0);
    const int m = min(bcur[b], CAP);
    const int mS = min(bcurS[b], CAP);
    const int* pk = packed + (size_t)b * CAP;
    const unsigned char* pkS = packedS + (size_t)b * CAP;

    cnt[tid] = 0;
    cntS[tid] = 0;
    __syncthreads();
    for (int i = tid; i < m; i += 256) atomicAdd(&cnt[pk[i] & 255], 1);
    for (int i = tid; i < mS; i += 256) atomicAdd(&cntS[(int)pkS[i]], 1);
    __syncthreads();
    int c = cnt[tid];
    sc[tid] = c;
    __syncthreads();
    for (int off = 1; off < 256; off <<= 1) {
        int t = (tid >= off) ? sc[tid - off] : 0;
        __syncthreads();
        sc[tid] += t;
        __syncthreads();
    }
    int excl = sc[tid] - c;
    cur[tid] = excl;
    if (tid < nn) {
        int v = n0 + tid;
        int beg = b * CAP + excl;
        row_beg[v] = beg;
        row_end[v] = beg + c;
        nd[v] = (c > 0) ? rsqrtf((float)c) : 0.0f;
        int dg = cntS[tid];
        ns[v] = (dg > 0) ? rsqrtf((float)dg) : 0.0f;
    }
    __syncthreads();
    for (int i = tid; i < m; i += 256) {
        int w = pk[i];
        int v = w & 255;
        int p = atomicAdd(&cur[v], 1);  // LDS
        csr_src[(size_t)b * CAP + p] = w >> 8;
    }
}

// ---------------- scale Hb0 rows by ns (deferred layer-0 ns; full parallelism) ----------------
__global__ __launch_bounds__(256) void k_scale_h(unsigned int* __restrict__ Hd,
                                                 const float* __restrict__ ns,
                                                 int n) {
    int i = blockIdx.x * 256 + threadIdx.x; // dword index, 32 dwords/row
    if (i < n * 32) {
        int row = i >> 5;
        float s = ns[row];
        unsigned int u = Hd[i];
        float lo = bf2f((unsigned short)(u & 0xffffu)) * s;
        float hi = bf2f((unsigned short)(u >> 16)) * s;
        Hd[i] = (unsigned int)f2bf(lo) | ((unsigned int)f2bf(hi) << 16);
    }
}

// ---------------- GEMM (K=64): C = bf16((A @ W) * ns[row]) ----------------
template <int OUT>
__global__ __launch_bounds__(256, 4) void k_gemm_scale(const float* __restrict__ A,
                                                       const float* __restrict__ W,
                                                       const float* __restrict__ ns,
                                                       unsigned short* __restrict__ C,
                                                       int n) {
    __shared__ __align__(16) float Ws[64 * 64];
    __shared__ __align__(16) float Asm[64 * 68];

    const int tid = threadIdx.x;
    const int r0 = blockIdx.x * 64;

    for (int i = tid; i < 64 * 64; i += 256) {
        int k = i >> 6;
        int c = i & 63;
        Ws[i] = (c < OUT) ? W[k * OUT + c] : 0.0f;
    }
    for (int i = tid * 4; i < 64 * 64; i += 1024) {
        int r = i >> 6;
        int c = i & 63;
        f4 v;
        if (r0 + r < n) {
            v = *(const f4*)&A[(size_t)(r0 + r) * 64 + c];
        } else {
            v.v[0] = v.v[1] = v.v[2] = v.v[3] = 0.0f;
        }
        *(f4*)&Asm[r * 68 + c] = v;
    }
    __syncthreads();

    const int tr = tid >> 4;
    const int tc = tid & 15;

    float acc[4][4];
#pragma unroll
    for (int i = 0; i < 4; ++i)
#pragma unroll
        for (int j = 0; j < 4; ++j) acc[i][j] = 0.0f;

    for (int k = 0; k < 64; k += 4) {
        f4 av[4], wv[4];
#pragma unroll
        for (int i = 0; i < 4; ++i)
            av[i] = *(const f4*)&Asm[(tr * 4 + i) * 68 + k];
#pragma unroll
        for (int kk = 0; kk < 4; ++kk)
            wv[kk] = *(const f4*)&Ws[(k + kk) * 64 + tc * 4];
#pragma unroll
        for (int i = 0; i < 4; ++i)
#pragma unroll
            for (int j = 0; j < 4; ++j)
                acc[i][j] += av[i].v[0] * wv[0].v[j] + av[i].v[1] * wv[1].v[j] +
                             av[i].v[2] * wv[2].v[j] + av[i].v[3] * wv[3].v[j];
    }

    if (tc * 4 < OUT) {
#pragma unroll
        for (int i = 0; i < 4; ++i) {
            int row = r0 + tr * 4 + i;
            if (row < n) {
                float s = ns[row];
                us4 o;
#pragma unroll
                for (int j = 0; j < 4; ++j) o.v[j] = f2bf(acc[i][j] * s);
                *(us4*)&C[(size_t)row * OUT + tc * 4] = o;
            }
        }
    }
}

// ---------------- fused CSR aggregate (bf16 gather) + (*nd + b) + relu? + log_softmax ----------------
// One node per 64-lane wave; per-lane vector index load + __shfl broadcast (R7-proven).
template <int D, bool RELU>
__global__ __launch_bounds__(256) void k_agg_post(const int* __restrict__ row_beg,
                                                  const int* __restrict__ row_end,
                                                  const int* __restrict__ csr_src,
                                                  const unsigned short* __restrict__ H,
                                                  const float* __restrict__ nd,
                                                  const float* __restrict__ b,
                                                  float* __restrict__ Out,
                                                  int n) {
    int node = blockIdx.x * 4 + (threadIdx.x >> 6);
    int lane = threadIdx.x & 63;
    if (node >= n) return;

    int beg = row_beg[node];
    int end = row_end[node];
    bool active = lane < D;

    float a0 = 0.f, a1 = 0.f, a2 = 0.f, a3 = 0.f;
    for (int i = beg; i < end; i += 64) {
        int cnt = min(64, end - i);
        int idx = (lane < cnt) ? csr_src[i + lane] : 0;
        int j = 0;
        for (; j + 4 <= cnt; j += 4) {
            int s0 = __shfl(idx, j);
            int s1 = __shfl(idx, j + 1);
            int s2 = __shfl(idx, j + 2);
            int s3 = __shfl(idx, j + 3);
            if (active) {
                a0 += bf2f(H[(size_t)s0 * D + lane]);
                a1 += bf2f(H[(size_t)s1 * D + lane]);
                a2 += bf2f(H[(size_t)s2 * D + lane]);
                a3 += bf2f(H[(size_t)s3 * D + lane]);
            }
        }
        for (; j < cnt; ++j) {
            int s = __shfl(idx, j);
            if (active) a0 += bf2f(H[(size_t)s * D + lane]);
        }
    }
    float acc = (a0 + a1) + (a2 + a3);

    float x = -INFINITY;
    if (active) {
        x = acc * nd[node] + b[lane];
        if (RELU) x = fmaxf(x, 0.0f);
    }
    float m = x;
#pragma unroll
    for (int off = 32; off > 0; off >>= 1) m = fmaxf(m, __shfl_xor(m, off));
    float ex = active ? expf(x - m) : 0.0f;
    float ssum = ex;
#pragma unroll
    for (int off = 32; off > 0; off >>= 1) ssum += __shfl_xor(ssum, off);
    if (active) Out[(size_t)node * D + lane] = (x - m) - logf(ssum);
}

extern "C" void kernel_launch(void* const* d_in, const int* in_sizes, int n_in,
                              void* d_out, int out_size, void* d_ws, size_t ws_size,
                              hipStream_t stream) {
    const float* feats = (const float*)d_in[0];
    const int* src = (const int*)d_in[1];
    const int* dst = (const int*)d_in[2];
    const float* W0 = (const float*)d_in[3];
    const float* b0 = (const float*)d_in[4];
    const float* W1 = (const float*)d_in[5];
    const float* b1 = (const float*)d_in[6];
    const float* W2 = (const float*)d_in[7];
    const float* b2 = (const float*)d_in[8];
    float* out = (float*)d_out;

    const int N = N_NODES;
    const int E = in_sizes[1];
    const int GT = (N + 63) / 64;                       // 1563 gemm tiles
    const int NCHUNK = (E + ACHUNK - 1) / ACHUNK;       // 1563 pass-A chunks
    const int grid1 = GT + NCHUNK;
    int S = grid1 / NCHUNK;                             // interleave stride (=2)
    if (S < 1) S = 1;

    // workspace layout (~69 MB)
    float* ns = (float*)d_ws;                           // N
    float* nd = ns + N;                                 // N
    unsigned short* Hb = (unsigned short*)(nd + N);     // N*64 bf16
    float* G = (float*)(Hb + (size_t)N * 64);           // N*64 fp32
    int* packed = (int*)(G + (size_t)N * 64);           // NBUCK*CAP ints
    int* csr_src = packed + (size_t)NBUCK * CAP;        // NBUCK*CAP ints
    int* row_beg = csr_src + (size_t)NBUCK * CAP;       // N
    int* row_end = row_beg + N;                         // N
    int* bcur = row_end + N;                            // NBUCK
    int* bcurS = bcur + NBUCK;                          // NBUCK
    unsigned char* packedS = (unsigned char*)(bcurS + NBUCK); // NBUCK*CAP bytes

    hipMemsetAsync(bcur, 0, (size_t)2 * NBUCK * sizeof(int), stream);

    // 1) interleaved dual-partition + layer-0 GEMM (unscaled)
    k_passA_gemm0<<<grid1, 256, 0, stream>>>(src, dst, E, NCHUNK, S, bcur, bcurS,
                                             packed, packedS, feats, W0, Hb, N);

    // 2) per-bucket CSR build + norms
    k_passB<<<NBUCK, 256, 0, stream>>>(bcur, bcurS, packed, packedS, csr_src,
                                       row_beg, row_end, ns, nd, N);

    // 3) deferred layer-0 ns scale (full parallelism)
    k_scale_h<<<(N * 32 + 255) / 256, 256, 0, stream>>>((unsigned int*)Hb, ns, N);

    const int agg_blocks = (N + 3) / 4;

    // ---- layer 0 agg + relu + log_softmax -> G ----
    k_agg_post<64, true><<<agg_blocks, 256, 0, stream>>>(row_beg, row_end, csr_src, Hb, nd, b0, G, N);

    // ---- layer 1 ----
    k_gemm_scale<64><<<GT, 256, 0, stream>>>(G, W1, ns, Hb, N);
    k_agg_post<64, true><<<agg_blocks, 256, 0, stream>>>(row_beg, row_end, csr_src, Hb, nd, b1, G, N);

    // ---- layer 2 ----
    k_gemm_scale<40><<<GT, 256, 0, stream>>>(G, W2, ns, Hb, N);
    k_agg_post<40, false><<<agg_blocks, 256, 0, stream>>>(row_beg, row_end, csr_src, Hb, nd, b2, out, N);
}